// Round 11
// baseline (211.914 us; speedup 1.0000x reference)
//
#include <hip/hip_runtime.h>

#define NNODES 100000
#define NEDGES 600000
#define D 128

typedef short bf16x8 __attribute__((ext_vector_type(8)));
typedef float f32x4  __attribute__((ext_vector_type(4)));

// prep grid: b in [0,9376): bb4=b>>2, rem=b&3; rem<3 -> tobf16 t=bb4*3+rem
// (valid t<6250); rem==3 -> build block bb4 (2344 blocks, co-resident with
// tobf16 throughout). b in [9376,9440): wprep.
#define PREP_MAIN 9376
#define PREP_BLOCKS (PREP_MAIN + 64)

__device__ __forceinline__ unsigned short f2bf(float f) {
    unsigned u = __float_as_uint(f);
    unsigned r = (u + 0x7FFFu + ((u >> 16) & 1u)) >> 16;
    return (unsigned short)r;
}
__device__ __forceinline__ float bf2f(unsigned short h) {
    return __uint_as_float(((unsigned)h) << 16);
}

// ---------------------------------------------------------------------------
// Fused prep, role-interleaved (round-10 proven version, unchanged):
//   tobf16: x fp32 -> xb bf16 row-major, 8 floats/thread, one 16-B store.
//   build:  linked-list adjacency, payload packed with pointer:
//           nn_f[e] = {src, old_head_f[dst]}  (in-edge chain of dst)
//           nn_b[e] = {dst, old_head_b[src]}  (out-edge chain of src)
//           -> k_mean does ONE 8-B load per hop. heads pre-set to -1.
//   wprep:  weights -> bf16 wcat {wl_f, wl_b, wr_f+wr_b}; bias sum.
// ---------------------------------------------------------------------------
__global__ __launch_bounds__(256) void k_prep(
    const float* __restrict__ x, const int* __restrict__ ei,
    const float* __restrict__ wl_f, const float* __restrict__ wl_b,
    const float* __restrict__ wr_f, const float* __restrict__ wr_b,
    const float* __restrict__ bl_f, const float* __restrict__ bl_b,
    unsigned short* __restrict__ xb,
    int* __restrict__ head_f, int2* __restrict__ nn_f,
    int* __restrict__ head_b, int2* __restrict__ nn_b,
    unsigned short* __restrict__ wcat, float* __restrict__ bb)
{
    const int b = blockIdx.x;
    if (b < PREP_MAIN) {
        const int bb4 = b >> 2;
        const int rem = b & 3;
        if (rem < 3) {
            int t = bb4 * 3 + rem;                    // [0, 7032); valid < 6250
            if (t >= NNODES * D / 8) return;
            size_t base = ((size_t)t * 256 + threadIdx.x) * 8;   // float index
            if (base >= (size_t)NNODES * D) return;
            float4 v0 = *(const float4*)(x + base);
            float4 v1 = *(const float4*)(x + base + 4);
            ushort4 o0, o1;
            o0.x = f2bf(v0.x); o0.y = f2bf(v0.y); o0.z = f2bf(v0.z); o0.w = f2bf(v0.w);
            o1.x = f2bf(v1.x); o1.y = f2bf(v1.y); o1.z = f2bf(v1.z); o1.w = f2bf(v1.w);
            uint4 o;
            o.x = (unsigned)o0.x | ((unsigned)o0.y << 16);
            o.y = (unsigned)o0.z | ((unsigned)o0.w << 16);
            o.z = (unsigned)o1.x | ((unsigned)o1.y << 16);
            o.w = (unsigned)o1.z | ((unsigned)o1.w << 16);
            *(uint4*)(xb + base) = o;
        } else {
            int e = bb4 * 256 + threadIdx.x;
            if (e >= NEDGES) return;
            int s = ei[e];
            int d = ei[NEDGES + e];
            s = min(max(s, 0), NNODES - 1);
            d = min(max(d, 0), NNODES - 1);
            nn_f[e] = make_int2(s, atomicExch(&head_f[d], e));
            nn_b[e] = make_int2(d, atomicExch(&head_b[s], e));
        }
    } else {
        int i = (b - PREP_MAIN) * 256 + threadIdx.x;
        if (i >= 128 * 128) return;
        wcat[i]         = f2bf(wl_f[i]);
        wcat[16384 + i] = f2bf(wl_b[i]);
        wcat[32768 + i] = f2bf(wr_f[i] + wr_b[i]);
        if (i < 128) bb[i] = bl_f[i] + bl_b[i];
    }
}

// ---------------------------------------------------------------------------
// Chain-walk gather means (round-10 proven version, unchanged). One 32-lane
// group per (node, dir); lane owns 4 columns (8B). Hop = one 8-B nn load +
// one 256-B row gather. Each chain walked exactly once globally.
// Writes bf16 means interleaved into d_out:
//   meanpair[n] = { mean_f[n] (256B) , mean_b[n] (256B) }
// Bound by compulsory per-XCD x-replication at random-line service rate --
// falsified as latency-bound (r6) and as sliceable (r9).
// ---------------------------------------------------------------------------
__global__ __launch_bounds__(256) void k_mean(
    const unsigned short* __restrict__ xb,
    const int* __restrict__ head_f, const int2* __restrict__ nn_f,
    const int* __restrict__ head_b, const int2* __restrict__ nn_b,
    unsigned short* __restrict__ meanpair)   // [N][256] bf16
{
    int g = (blockIdx.x * 256 + threadIdx.x) >> 5;
    int lane = threadIdx.x & 31;
    if (g >= 2 * NNODES) return;
    const int dir = (g >= NNODES);
    const int n = dir ? g - NNODES : g;
    const int* head = dir ? head_b : head_f;
    const int2* nn  = dir ? nn_b  : nn_f;

    float a0 = 0.f, a1 = 0.f, a2 = 0.f, a3 = 0.f;
    int cnt = 0;
    int e = head[n];
    for (int it = 0; it < NEDGES && e >= 0; ++it) {
        int2 v = nn[e];
        int nbr = min(max(v.x, 0), NNODES - 1);
        ushort4 u = *(const ushort4*)(xb + (size_t)nbr * D + lane * 4);
        a0 += bf2f(u.x); a1 += bf2f(u.y); a2 += bf2f(u.z); a3 += bf2f(u.w);
        ++cnt;
        e = v.y;
    }
    float sc = 1.0f / (float)max(cnt, 1);
    ushort4 o;
    o.x = f2bf(a0 * sc); o.y = f2bf(a1 * sc); o.z = f2bf(a2 * sc); o.w = f2bf(a3 * sc);
    *(ushort4*)(meanpair + (size_t)n * 256 + dir * 128 + lane * 4) = o;
}

// ---------------------------------------------------------------------------
// LDS-FREE MFMA GEMM + bias + relu.
// out[N,128] = relu(0.5*( A @ Wcat^T-concat + bb )), A k-segs:
//   k32 0..7:  A = meanpair rows (512B: mean_f 256B | mean_b 256B)
//   k32 8..11: A = xb rows (256B)
// Key fact: for mfma_f32_16x16x32_bf16 the A/B fragment is lane(l15=row,
// l4=k-chunk) -> a wave's 4 l4-lanes cover one row's CONTIGUOUS 64B, and all
// row strides (512/256B) are 64B-aligned -> direct global loads are fully
// 64B-line-efficient. No LDS, no barriers; W (96KB wcat) is L2-resident.
// #pragma unroll 2 pipelines loads without VGPR spill. OOB rows clamp to
// N-1; garbage acc rows discarded in the epilogue. d_out aliasing: block
// reads only its own 128 meanpair rows, writes exactly those bytes.
// ---------------------------------------------------------------------------
__global__ __launch_bounds__(256) void gemm_mfma(
    const unsigned char* __restrict__ meanpair,  // [N][512B]
    const unsigned char* __restrict__ xb,        // [N][256B]
    const unsigned char* __restrict__ wcat,      // [3][128][256B]
    const float* __restrict__ bb,
    float* __restrict__ out)
{
    const int tid = threadIdx.x;
    const int n0 = blockIdx.x * 128;
    const int wv = tid >> 6;
    const int wr = wv >> 1, wc = wv & 1;
    const int lane = tid & 63;
    const int l15 = lane & 15, l4 = lane >> 4;
    const int colb = l4 * 16;            // lane's 16B chunk within a 64B k-slab

    f32x4 acc[4][4];
#pragma unroll
    for (int i = 0; i < 4; ++i)
#pragma unroll
        for (int j = 0; j < 4; ++j)
            acc[i][j] = (f32x4){0.f, 0.f, 0.f, 0.f};

    size_t arow[4];
#pragma unroll
    for (int i = 0; i < 4; ++i) {
        int row = n0 + wr * 64 + i * 16 + l15;
        arow[i] = (size_t)min(row, NNODES - 1);
    }
    const unsigned char* wrow[4];
#pragma unroll
    for (int j = 0; j < 4; ++j) {
        int c = wc * 64 + j * 16 + l15;
        wrow[j] = wcat + (size_t)c * 256 + colb;
    }

    // k32 slabs 0..7: A from meanpair (byte k32*64 within the 512B row);
    // W seg = k32>>2, within-seg byte (k32&3)*64.
#pragma unroll 2
    for (int k32 = 0; k32 < 8; ++k32) {
        bf16x8 af[4], bf[4];
#pragma unroll
        for (int i = 0; i < 4; ++i)
            af[i] = *(const bf16x8*)(meanpair + arow[i] * 512 + k32 * 64 + colb);
#pragma unroll
        for (int j = 0; j < 4; ++j)
            bf[j] = *(const bf16x8*)(wrow[j] + (k32 >> 2) * 32768 + (k32 & 3) * 64);
#pragma unroll
        for (int i = 0; i < 4; ++i)
#pragma unroll
            for (int j = 0; j < 4; ++j)
                acc[i][j] = __builtin_amdgcn_mfma_f32_16x16x32_bf16(
                    af[i], bf[j], acc[i][j], 0, 0, 0);
    }
    // k32 slabs 8..11: A from xb, W seg 2.
#pragma unroll 2
    for (int k32 = 0; k32 < 4; ++k32) {
        bf16x8 af[4], bf[4];
#pragma unroll
        for (int i = 0; i < 4; ++i)
            af[i] = *(const bf16x8*)(xb + arow[i] * 256 + k32 * 64 + colb);
#pragma unroll
        for (int j = 0; j < 4; ++j)
            bf[j] = *(const bf16x8*)(wrow[j] + 2 * 32768 + k32 * 64);
#pragma unroll
        for (int i = 0; i < 4; ++i)
#pragma unroll
            for (int j = 0; j < 4; ++j)
                acc[i][j] = __builtin_amdgcn_mfma_f32_16x16x32_bf16(
                    af[i], bf[j], acc[i][j], 0, 0, 0);
    }

    // epilogue: D-tile mapping col=lane&15, row=(lane>>4)*4+r
#pragma unroll
    for (int i = 0; i < 4; ++i) {
        int row0 = n0 + wr * 64 + i * 16 + l4 * 4;
#pragma unroll
        for (int j = 0; j < 4; ++j) {
            int col = wc * 64 + j * 16 + l15;
            float b = bb[col];
#pragma unroll
            for (int r = 0; r < 4; ++r) {
                int row = row0 + r;
                if (row < NNODES) {
                    float v = 0.5f * (acc[i][j][r] + b);
                    out[(size_t)row * 128 + col] = v > 0.f ? v : 0.f;
                }
            }
        }
    }
}

extern "C" void kernel_launch(void* const* d_in, const int* in_sizes, int n_in,
                              void* d_out, int out_size, void* d_ws, size_t ws_size,
                              hipStream_t stream)
{
    const float* x  = (const float*)d_in[0];
    const int*   ei = (const int*)d_in[1];   // int64 in reference -> int32 here
    const float* wl_f = (const float*)d_in[3];
    const float* bl_f = (const float*)d_in[4];
    const float* wr_f = (const float*)d_in[5];
    const float* wl_b = (const float*)d_in[6];
    const float* bl_b = (const float*)d_in[7];
    const float* wr_b = (const float*)d_in[8];
    float* out = (float*)d_out;

    // ws layout (~36 MB): xb | wcat | bb | head_f | head_b | nn_f | nn_b
    unsigned short* xb   = (unsigned short*)d_ws;                 // N*D bf16
    unsigned short* wcat = xb + (size_t)NNODES * D;               // 3*128*128
    float* bb   = (float*)(wcat + 3 * 128 * 128);                 // 128
    int* head_f = (int*)(bb + 128);
    int* head_b = head_f + NNODES;
    int2* nn_f  = (int2*)(head_b + NNODES);
    int2* nn_b  = nn_f + NEDGES;
    unsigned short* meanpair = (unsigned short*)d_out;  // [N][256] bf16, overwritten by gemm

    // head_* = -1
    hipMemsetAsync(head_f, 0xFF, 2 * (size_t)NNODES * sizeof(int), stream);

    dim3 b256(256);
    k_prep<<<dim3(PREP_BLOCKS), b256, 0, stream>>>(
        x, ei, wl_f, wl_b, wr_f, wr_b, bl_f, bl_b,
        xb, head_f, nn_f, head_b, nn_b, wcat, bb);

    dim3 gMean(((size_t)2 * NNODES * 32 + 255) / 256);
    k_mean<<<gMean, b256, 0, stream>>>(xb, head_f, nn_f, head_b, nn_b, meanpair);

    dim3 gG((NNODES + 127) / 128);
    gemm_mfma<<<gG, b256, 0, stream>>>((const unsigned char*)meanpair,
                                       (const unsigned char*)xb,
                                       (const unsigned char*)wcat, bb, out);
}

// Round 12
// 196.820 us; speedup vs baseline: 1.0767x; 1.0767x over previous
//
#include <hip/hip_runtime.h>

#define NNODES 100000
#define NEDGES 600000
#define D 128

typedef short bf16x8 __attribute__((ext_vector_type(8)));
typedef float f32x4  __attribute__((ext_vector_type(4)));

// prep grid: b in [0,9376): bb4=b>>2, rem=b&3; rem<3 -> tobf16 t=bb4*3+rem
// (valid t<6250); rem==3 -> build block bb4 (2344 blocks, co-resident with
// tobf16 throughout). b in [9376,9440): wprep.
#define PREP_MAIN 9376
#define PREP_BLOCKS (PREP_MAIN + 64)

__device__ __forceinline__ unsigned short f2bf(float f) {
    unsigned u = __float_as_uint(f);
    unsigned r = (u + 0x7FFFu + ((u >> 16) & 1u)) >> 16;
    return (unsigned short)r;
}
__device__ __forceinline__ float bf2f(unsigned short h) {
    return __uint_as_float(((unsigned)h) << 16);
}

// wave-collective async global->LDS, 16B/lane (dest = uniform base + lane*16)
__device__ __forceinline__ void gl_lds16(const unsigned char* g, unsigned char* l) {
    __builtin_amdgcn_global_load_lds(
        (const __attribute__((address_space(1))) unsigned int*)g,
        (__attribute__((address_space(3))) unsigned int*)l, 16, 0, 0);
}

// ---------------------------------------------------------------------------
// Fused prep, role-interleaved (round-10 proven version, unchanged):
//   tobf16: x fp32 -> xb bf16 row-major, 8 floats/thread, one 16-B store.
//   build:  linked-list adjacency, payload packed with pointer:
//           nn_f[e] = {src, old_head_f[dst]}  (in-edge chain of dst)
//           nn_b[e] = {dst, old_head_b[src]}  (out-edge chain of src)
//           -> k_mean does ONE 8-B load per hop. heads pre-set to -1.
//   wprep:  weights -> bf16 wcat {wl_f, wl_b, wr_f+wr_b}; bias sum.
// ---------------------------------------------------------------------------
__global__ __launch_bounds__(256) void k_prep(
    const float* __restrict__ x, const int* __restrict__ ei,
    const float* __restrict__ wl_f, const float* __restrict__ wl_b,
    const float* __restrict__ wr_f, const float* __restrict__ wr_b,
    const float* __restrict__ bl_f, const float* __restrict__ bl_b,
    unsigned short* __restrict__ xb,
    int* __restrict__ head_f, int2* __restrict__ nn_f,
    int* __restrict__ head_b, int2* __restrict__ nn_b,
    unsigned short* __restrict__ wcat, float* __restrict__ bb)
{
    const int b = blockIdx.x;
    if (b < PREP_MAIN) {
        const int bb4 = b >> 2;
        const int rem = b & 3;
        if (rem < 3) {
            int t = bb4 * 3 + rem;                    // [0, 7032); valid < 6250
            if (t >= NNODES * D / 8) return;
            size_t base = ((size_t)t * 256 + threadIdx.x) * 8;   // float index
            if (base >= (size_t)NNODES * D) return;
            float4 v0 = *(const float4*)(x + base);
            float4 v1 = *(const float4*)(x + base + 4);
            ushort4 o0, o1;
            o0.x = f2bf(v0.x); o0.y = f2bf(v0.y); o0.z = f2bf(v0.z); o0.w = f2bf(v0.w);
            o1.x = f2bf(v1.x); o1.y = f2bf(v1.y); o1.z = f2bf(v1.z); o1.w = f2bf(v1.w);
            uint4 o;
            o.x = (unsigned)o0.x | ((unsigned)o0.y << 16);
            o.y = (unsigned)o0.z | ((unsigned)o0.w << 16);
            o.z = (unsigned)o1.x | ((unsigned)o1.y << 16);
            o.w = (unsigned)o1.z | ((unsigned)o1.w << 16);
            *(uint4*)(xb + base) = o;
        } else {
            int e = bb4 * 256 + threadIdx.x;
            if (e >= NEDGES) return;
            int s = ei[e];
            int d = ei[NEDGES + e];
            s = min(max(s, 0), NNODES - 1);
            d = min(max(d, 0), NNODES - 1);
            nn_f[e] = make_int2(s, atomicExch(&head_f[d], e));
            nn_b[e] = make_int2(d, atomicExch(&head_b[s], e));
        }
    } else {
        int i = (b - PREP_MAIN) * 256 + threadIdx.x;
        if (i >= 128 * 128) return;
        wcat[i]         = f2bf(wl_f[i]);
        wcat[16384 + i] = f2bf(wl_b[i]);
        wcat[32768 + i] = f2bf(wr_f[i] + wr_b[i]);
        if (i < 128) bb[i] = bl_f[i] + bl_b[i];
    }
}

// ---------------------------------------------------------------------------
// Chain-walk gather means (round-10 proven version, unchanged). One 32-lane
// group per (node, dir); lane owns 4 columns (8B). Hop = one 8-B nn load +
// one 256-B row gather. Each chain walked exactly once globally.
// Writes bf16 means interleaved into d_out:
//   meanpair[n] = { mean_f[n] (256B) , mean_b[n] (256B) }
// Bound by compulsory per-XCD x-replication at random-line service rate --
// falsified as latency-bound (r6) and as sliceable (r9).
// ---------------------------------------------------------------------------
__global__ __launch_bounds__(256) void k_mean(
    const unsigned short* __restrict__ xb,
    const int* __restrict__ head_f, const int2* __restrict__ nn_f,
    const int* __restrict__ head_b, const int2* __restrict__ nn_b,
    unsigned short* __restrict__ meanpair)   // [N][256] bf16
{
    int g = (blockIdx.x * 256 + threadIdx.x) >> 5;
    int lane = threadIdx.x & 31;
    if (g >= 2 * NNODES) return;
    const int dir = (g >= NNODES);
    const int n = dir ? g - NNODES : g;
    const int* head = dir ? head_b : head_f;
    const int2* nn  = dir ? nn_b  : nn_f;

    float a0 = 0.f, a1 = 0.f, a2 = 0.f, a3 = 0.f;
    int cnt = 0;
    int e = head[n];
    for (int it = 0; it < NEDGES && e >= 0; ++it) {
        int2 v = nn[e];
        int nbr = min(max(v.x, 0), NNODES - 1);
        ushort4 u = *(const ushort4*)(xb + (size_t)nbr * D + lane * 4);
        a0 += bf2f(u.x); a1 += bf2f(u.y); a2 += bf2f(u.z); a3 += bf2f(u.w);
        ++cnt;
        e = v.y;
    }
    float sc = 1.0f / (float)max(cnt, 1);
    ushort4 o;
    o.x = f2bf(a0 * sc); o.y = f2bf(a1 * sc); o.z = f2bf(a2 * sc); o.w = f2bf(a3 * sc);
    *(ushort4*)(meanpair + (size_t)n * 256 + dir * 128 + lane * 4) = o;
}

// ---------------------------------------------------------------------------
// MFMA GEMM + bias + relu. A staged via global_load_lds (round-8 proven);
// W read DIRECT from global into registers (wcat is 96KB, L2-resident --
// r11 showed duplicating A from HBM is a 25us loss, but W duplication across
// wr-waves is only ~150MB of L2 traffic ~= 4us chip-wide). Per kstep:
//   sync -> prefetch 8 W fragments to regs -> issue 4 A-DMAs -> sync
//   (barrier drains vmcnt: both W regs and A LDS valid) -> 32 MFMAs.
// Halves the per-barrier DMA queue (8->4/wave), drops Wsm (LDS 32->16KB),
// removes 4 ds_reads per ks. A-side swizzle unchanged: linear LDS dest,
// XOR (byte ^= (row&7)<<4) pre-applied to the global source address.
// OOB rows clamp to N-1; garbage acc rows discarded in epilogue. d_out
// aliasing: block reads only its own 128 meanpair rows, writes those bytes.
// ---------------------------------------------------------------------------
__global__ __launch_bounds__(256) void gemm_mfma(
    const unsigned char* __restrict__ meanpair,  // [N][512B]
    const unsigned char* __restrict__ xb,        // [N][256B]
    const unsigned char* __restrict__ wcat,      // [3][128][256B]
    const float* __restrict__ bb,
    float* __restrict__ out)
{
    __shared__ unsigned char Asm[16384];   // 128 rows x 128B, swizzled layout

    const int tid = threadIdx.x;
    const int n0 = blockIdx.x * 128;
    const int wv = tid >> 6;
    const int wr = wv >> 1, wc = wv & 1;
    const int lane = tid & 63;
    const int l15 = lane & 15, l4 = lane >> 4;
    const int rowl = lane >> 3;                       // 0..7 within 8-row chunk
    const int xorcol = (((lane & 7) ^ rowl) << 4);    // pre-swizzled source col

    f32x4 acc[4][4];
#pragma unroll
    for (int i = 0; i < 4; ++i)
#pragma unroll
        for (int j = 0; j < 4; ++j)
            acc[i][j] = (f32x4){0.f, 0.f, 0.f, 0.f};

    // per-lane W row base: col c = wc*64 + j*16 + l15, 16B chunk l4
    const unsigned char* wrow[4];
#pragma unroll
    for (int j = 0; j < 4; ++j) {
        int c = wc * 64 + j * 16 + l15;
        wrow[j] = wcat + (size_t)c * 256 + l4 * 16;
    }

    for (int kstep = 0; kstep < 6; ++kstep) {
        const int seg  = kstep >> 1;
        const int ks0b = (kstep & 1) * 128;   // byte offset into seg's 256B k-range
        __syncthreads();                      // all waves done reading Asm
        // W prefetch to regs: 2 ks x 4 j fragments (L2-resident wcat)
        bf16x8 bf[2][4];
#pragma unroll
        for (int ks = 0; ks < 2; ++ks)
#pragma unroll
            for (int j = 0; j < 4; ++j)
                bf[ks][j] = *(const bf16x8*)(wrow[j] + seg * 32768 + ks0b + ks * 64);
        // stage A: wave wv covers rows [wv*32, wv*32+32), 4 x 1KB DMA
#pragma unroll
        for (int t = 0; t < 4; ++t) {
            int row = n0 + wv * 32 + t * 8 + rowl;
            int rowc = min(row, NNODES - 1);
            const unsigned char* src = (seg < 2)
                ? meanpair + (size_t)rowc * 512 + seg * 256 + ks0b + xorcol
                : xb + (size_t)rowc * 256 + ks0b + xorcol;
            gl_lds16(src, Asm + wv * 4096 + t * 1024);
        }
        __syncthreads();                      // drains vmcnt (DMA + W complete)
        // compute: two K=32 slabs
#pragma unroll
        for (int ks = 0; ks < 2; ++ks) {
            const int kb = ks * 64 + l4 * 16;
            bf16x8 af[4];
#pragma unroll
            for (int i = 0; i < 4; ++i) {
                int row = wr * 64 + i * 16 + l15;
                af[i] = *(const bf16x8*)(Asm + row * 128 + (kb ^ ((row & 7) << 4)));
            }
#pragma unroll
            for (int i = 0; i < 4; ++i)
#pragma unroll
                for (int j = 0; j < 4; ++j)
                    acc[i][j] = __builtin_amdgcn_mfma_f32_16x16x32_bf16(
                        af[i], bf[ks][j], acc[i][j], 0, 0, 0);
        }
    }

    // epilogue: D-tile mapping col=lane&15, row=(lane>>4)*4+r
#pragma unroll
    for (int i = 0; i < 4; ++i) {
        int row0 = n0 + wr * 64 + i * 16 + l4 * 4;
#pragma unroll
        for (int j = 0; j < 4; ++j) {
            int col = wc * 64 + j * 16 + l15;
            float b = bb[col];
#pragma unroll
            for (int r = 0; r < 4; ++r) {
                int row = row0 + r;
                if (row < NNODES) {
                    float v = 0.5f * (acc[i][j][r] + b);
                    out[(size_t)row * 128 + col] = v > 0.f ? v : 0.f;
                }
            }
        }
    }
}

extern "C" void kernel_launch(void* const* d_in, const int* in_sizes, int n_in,
                              void* d_out, int out_size, void* d_ws, size_t ws_size,
                              hipStream_t stream)
{
    const float* x  = (const float*)d_in[0];
    const int*   ei = (const int*)d_in[1];   // int64 in reference -> int32 here
    const float* wl_f = (const float*)d_in[3];
    const float* bl_f = (const float*)d_in[4];
    const float* wr_f = (const float*)d_in[5];
    const float* wl_b = (const float*)d_in[6];
    const float* bl_b = (const float*)d_in[7];
    const float* wr_b = (const float*)d_in[8];
    float* out = (float*)d_out;

    // ws layout (~36 MB): xb | wcat | bb | head_f | head_b | nn_f | nn_b
    unsigned short* xb   = (unsigned short*)d_ws;                 // N*D bf16
    unsigned short* wcat = xb + (size_t)NNODES * D;               // 3*128*128
    float* bb   = (float*)(wcat + 3 * 128 * 128);                 // 128
    int* head_f = (int*)(bb + 128);
    int* head_b = head_f + NNODES;
    int2* nn_f  = (int2*)(head_b + NNODES);
    int2* nn_b  = nn_f + NEDGES;
    unsigned short* meanpair = (unsigned short*)d_out;  // [N][256] bf16, overwritten by gemm

    // head_* = -1
    hipMemsetAsync(head_f, 0xFF, 2 * (size_t)NNODES * sizeof(int), stream);

    dim3 b256(256);
    k_prep<<<dim3(PREP_BLOCKS), b256, 0, stream>>>(
        x, ei, wl_f, wl_b, wr_f, wr_b, bl_f, bl_b,
        xb, head_f, nn_f, head_b, nn_b, wcat, bb);

    dim3 gMean(((size_t)2 * NNODES * 32 + 255) / 256);
    k_mean<<<gMean, b256, 0, stream>>>(xb, head_f, nn_f, head_b, nn_b, meanpair);

    dim3 gG((NNODES + 127) / 128);
    gemm_mfma<<<gG, b256, 0, stream>>>((const unsigned char*)meanpair,
                                       (const unsigned char*)xb,
                                       (const unsigned char*)wcat, bb, out);
}

// Round 13
// 182.685 us; speedup vs baseline: 1.1600x; 1.0774x over previous
//
#include <hip/hip_runtime.h>

#define NNODES 100000
#define NEDGES 600000
#define D 128

typedef short bf16x8 __attribute__((ext_vector_type(8)));
typedef float f32x4  __attribute__((ext_vector_type(4)));

// prep grid (r8-proven): bb6=b/6, rem=b%6; rem<5 -> tobf16 t=bb6*5+rem
// (12500 blocks, t exactly covers 3.2M float4s); rem==5 -> bb6<2344: build;
// bb6 in [2344,2408): wprep; rest idle.
#define PREP_BLOCKS 15000

__device__ __forceinline__ unsigned short f2bf(float f) {
    unsigned u = __float_as_uint(f);
    unsigned r = (u + 0x7FFFu + ((u >> 16) & 1u)) >> 16;
    return (unsigned short)r;
}
__device__ __forceinline__ float bf2f(unsigned short h) {
    return __uint_as_float(((unsigned)h) << 16);
}

// wave-collective async global->LDS, 16B/lane (dest = uniform base + lane*16)
__device__ __forceinline__ void gl_lds16(const unsigned char* g, unsigned char* l) {
    __builtin_amdgcn_global_load_lds(
        (const __attribute__((address_space(1))) unsigned int*)g,
        (__attribute__((address_space(3))) unsigned int*)l, 16, 0, 0);
}

// ---------------------------------------------------------------------------
// Fused prep, role-interleaved (r8-proven geometry + r10's int2-nn build):
//   tobf16: x fp32 -> xb bf16 row-major (float4/thread).
//   build:  linked-list adjacency, payload packed with pointer:
//           nn_f[e] = {src, old_head_f[dst]}  (in-edge chain of dst)
//           nn_b[e] = {dst, old_head_b[src]}  (out-edge chain of src)
//           -> k_mean does ONE 8-B load per hop. heads pre-set to -1.
//   wprep:  weights -> bf16 wcat {wl_f, wl_b, wr_f+wr_b}; bias sum.
// ---------------------------------------------------------------------------
__global__ __launch_bounds__(256) void k_prep(
    const float* __restrict__ x, const int* __restrict__ ei,
    const float* __restrict__ wl_f, const float* __restrict__ wl_b,
    const float* __restrict__ wr_f, const float* __restrict__ wr_b,
    const float* __restrict__ bl_f, const float* __restrict__ bl_b,
    unsigned short* __restrict__ xb,
    int* __restrict__ head_f, int2* __restrict__ nn_f,
    int* __restrict__ head_b, int2* __restrict__ nn_b,
    unsigned short* __restrict__ wcat, float* __restrict__ bb)
{
    const int b = blockIdx.x;
    const int bb6 = b / 6;
    const int rem = b - bb6 * 6;
    if (rem < 5) {
        int t = bb6 * 5 + rem;                    // [0,12500)
        int i = t * 256 + threadIdx.x;            // float4 index
        if (i >= NNODES * D / 4) return;
        float4 v = *(const float4*)(x + (size_t)i * 4);
        ushort4 o;
        o.x = f2bf(v.x); o.y = f2bf(v.y); o.z = f2bf(v.z); o.w = f2bf(v.w);
        *(ushort4*)(xb + (size_t)i * 4) = o;
    } else if (bb6 < 2344) {
        int e = bb6 * 256 + threadIdx.x;
        if (e >= NEDGES) return;
        int s = ei[e];
        int d = ei[NEDGES + e];
        s = min(max(s, 0), NNODES - 1);
        d = min(max(d, 0), NNODES - 1);
        nn_f[e] = make_int2(s, atomicExch(&head_f[d], e));
        nn_b[e] = make_int2(d, atomicExch(&head_b[s], e));
    } else if (bb6 < 2408) {
        int i = (bb6 - 2344) * 256 + threadIdx.x;
        if (i >= 128 * 128) return;
        wcat[i]         = f2bf(wl_f[i]);
        wcat[16384 + i] = f2bf(wl_b[i]);
        wcat[32768 + i] = f2bf(wr_f[i] + wr_b[i]);
        if (i < 128) bb[i] = bl_f[i] + bl_b[i];
    }
}

// ---------------------------------------------------------------------------
// Chain-walk gather means (r10-proven version, unchanged). One 32-lane
// group per (node, dir); lane owns 4 columns (8B). Hop = one 8-B nn load +
// one 256-B row gather. Each chain walked exactly once globally.
// Writes bf16 means interleaved into d_out:
//   meanpair[n] = { mean_f[n] (256B) , mean_b[n] (256B) }
// Bound by compulsory per-XCD x-replication (~8 x 25.6MB line sets) at the
// random-line service rate -- falsified as latency-bound (r6), as sliceable
// (r9); structure-packing (r10) gained the last 4us.
// ---------------------------------------------------------------------------
__global__ __launch_bounds__(256) void k_mean(
    const unsigned short* __restrict__ xb,
    const int* __restrict__ head_f, const int2* __restrict__ nn_f,
    const int* __restrict__ head_b, const int2* __restrict__ nn_b,
    unsigned short* __restrict__ meanpair)   // [N][256] bf16
{
    int g = (blockIdx.x * 256 + threadIdx.x) >> 5;
    int lane = threadIdx.x & 31;
    if (g >= 2 * NNODES) return;
    const int dir = (g >= NNODES);
    const int n = dir ? g - NNODES : g;
    const int* head = dir ? head_b : head_f;
    const int2* nn  = dir ? nn_b  : nn_f;

    float a0 = 0.f, a1 = 0.f, a2 = 0.f, a3 = 0.f;
    int cnt = 0;
    int e = head[n];
    for (int it = 0; it < NEDGES && e >= 0; ++it) {
        int2 v = nn[e];
        int nbr = min(max(v.x, 0), NNODES - 1);
        ushort4 u = *(const ushort4*)(xb + (size_t)nbr * D + lane * 4);
        a0 += bf2f(u.x); a1 += bf2f(u.y); a2 += bf2f(u.z); a3 += bf2f(u.w);
        ++cnt;
        e = v.y;
    }
    float sc = 1.0f / (float)max(cnt, 1);
    ushort4 o;
    o.x = f2bf(a0 * sc); o.y = f2bf(a1 * sc); o.z = f2bf(a2 * sc); o.w = f2bf(a3 * sc);
    *(ushort4*)(meanpair + (size_t)n * 256 + dir * 128 + lane * 4) = o;
}

// ---------------------------------------------------------------------------
// MFMA GEMM + bias + relu, r8 staging structure (A AND W via global_load_lds
// -- r11/r12 proved direct-load variants regress) at BM=64 for 2x TLP:
// 64x128 tile / block, 2 waves (each wave owns one 64-col half), 1563 blocks
// -> ~6 blocks/CU (12 waves/CU) so barrier-drain stalls of one block hide
// under another's compute (vs 3/CU at BM=128). LDS 24KB/block (6x fits).
// Per kstep per wave: 4 A-DMAs (rows wv*32..+32) + 8 W-DMAs (W rows
// wv*64..+64 = exactly the half this wave consumes). Swizzle: linear LDS
// dest, XOR (byte ^= (row&7)<<4) pre-applied to global source address.
// OOB rows clamp to N-1; garbage acc rows discarded in epilogue. d_out
// aliasing: block reads only its own 64 meanpair rows, writes those bytes.
// ---------------------------------------------------------------------------
__global__ __launch_bounds__(128) void gemm_mfma(
    const unsigned char* __restrict__ meanpair,  // [N][512B]
    const unsigned char* __restrict__ xb,        // [N][256B]
    const unsigned char* __restrict__ wcat,      // [3][128][256B]
    const float* __restrict__ bb,
    float* __restrict__ out)
{
    __shared__ unsigned char Asm[8192];    // 64 rows x 128B, swizzled layout
    __shared__ unsigned char Wsm[16384];   // 128 rows x 128B, swizzled layout

    const int tid = threadIdx.x;
    const int n0 = blockIdx.x * 64;
    const int wv = tid >> 6;                          // 0,1 = column half
    const int lane = tid & 63;
    const int l15 = lane & 15, l4 = lane >> 4;
    const int rowl = lane >> 3;                       // 0..7 within 8-row chunk
    const int xorcol = (((lane & 7) ^ rowl) << 4);    // pre-swizzled source col

    f32x4 acc[4][4];
#pragma unroll
    for (int i = 0; i < 4; ++i)
#pragma unroll
        for (int j = 0; j < 4; ++j)
            acc[i][j] = (f32x4){0.f, 0.f, 0.f, 0.f};

    for (int kstep = 0; kstep < 6; ++kstep) {
        const int seg  = kstep >> 1;
        const int ks0b = (kstep & 1) * 128;   // byte offset into seg's 256B k-range
        const int o    = ks0b + xorcol;
        __syncthreads();                      // all waves done reading LDS
        // stage A: 64 rows; wave wv covers rows [wv*32, wv*32+32), 4 x 1KB
#pragma unroll
        for (int t = 0; t < 4; ++t) {
            int row = n0 + wv * 32 + t * 8 + rowl;
            int rowc = min(row, NNODES - 1);
            const unsigned char* src = (seg < 2)
                ? meanpair + (size_t)rowc * 512 + seg * 256 + o
                : xb + (size_t)rowc * 256 + o;
            gl_lds16(src, Asm + wv * 4096 + t * 1024);
        }
        // stage W: 128 rows; wave wv covers rows [wv*64, wv*64+64), 8 x 1KB
#pragma unroll
        for (int t = 0; t < 8; ++t) {
            int c = wv * 64 + t * 8 + rowl;
            const unsigned char* src =
                wcat + seg * 32768 + (size_t)c * 256 + o;
            gl_lds16(src, Wsm + wv * 8192 + t * 1024);
        }
        __syncthreads();                      // drains vmcnt (DMA complete)
        // compute: two K=32 slabs
#pragma unroll
        for (int ks = 0; ks < 2; ++ks) {
            const int kb = ks * 64 + l4 * 16;
            bf16x8 af[4], bf[4];
#pragma unroll
            for (int i = 0; i < 4; ++i) {
                int row = i * 16 + l15;
                af[i] = *(const bf16x8*)(Asm + row * 128 + (kb ^ ((row & 7) << 4)));
            }
#pragma unroll
            for (int j = 0; j < 4; ++j) {
                int c = wv * 64 + j * 16 + l15;
                bf[j] = *(const bf16x8*)(Wsm + c * 128 + (kb ^ ((c & 7) << 4)));
            }
#pragma unroll
            for (int i = 0; i < 4; ++i)
#pragma unroll
                for (int j = 0; j < 4; ++j)
                    acc[i][j] = __builtin_amdgcn_mfma_f32_16x16x32_bf16(
                        af[i], bf[j], acc[i][j], 0, 0, 0);
        }
    }

    // epilogue: D-tile mapping col=lane&15, row=(lane>>4)*4+r
#pragma unroll
    for (int i = 0; i < 4; ++i) {
        int row0 = n0 + i * 16 + l4 * 4;
#pragma unroll
        for (int j = 0; j < 4; ++j) {
            int col = wv * 64 + j * 16 + l15;
            float b = bb[col];
#pragma unroll
            for (int r = 0; r < 4; ++r) {
                int row = row0 + r;
                if (row < NNODES) {
                    float v = 0.5f * (acc[i][j][r] + b);
                    out[(size_t)row * 128 + col] = v > 0.f ? v : 0.f;
                }
            }
        }
    }
}

extern "C" void kernel_launch(void* const* d_in, const int* in_sizes, int n_in,
                              void* d_out, int out_size, void* d_ws, size_t ws_size,
                              hipStream_t stream)
{
    const float* x  = (const float*)d_in[0];
    const int*   ei = (const int*)d_in[1];   // int64 in reference -> int32 here
    const float* wl_f = (const float*)d_in[3];
    const float* bl_f = (const float*)d_in[4];
    const float* wr_f = (const float*)d_in[5];
    const float* wl_b = (const float*)d_in[6];
    const float* bl_b = (const float*)d_in[7];
    const float* wr_b = (const float*)d_in[8];
    float* out = (float*)d_out;

    // ws layout (~36 MB): xb | wcat | bb | head_f | head_b | nn_f | nn_b
    unsigned short* xb   = (unsigned short*)d_ws;                 // N*D bf16
    unsigned short* wcat = xb + (size_t)NNODES * D;               // 3*128*128
    float* bb   = (float*)(wcat + 3 * 128 * 128);                 // 128
    int* head_f = (int*)(bb + 128);
    int* head_b = head_f + NNODES;
    int2* nn_f  = (int2*)(head_b + NNODES);
    int2* nn_b  = nn_f + NEDGES;
    unsigned short* meanpair = (unsigned short*)d_out;  // [N][256] bf16, overwritten by gemm

    // head_* = -1
    hipMemsetAsync(head_f, 0xFF, 2 * (size_t)NNODES * sizeof(int), stream);

    dim3 b256(256);
    k_prep<<<dim3(PREP_BLOCKS), b256, 0, stream>>>(
        x, ei, wl_f, wl_b, wr_f, wr_b, bl_f, bl_b,
        xb, head_f, nn_f, head_b, nn_b, wcat, bb);

    dim3 gMean(((size_t)2 * NNODES * 32 + 255) / 256);
    k_mean<<<gMean, b256, 0, stream>>>(xb, head_f, nn_f, head_b, nn_b, meanpair);

    dim3 gG((NNODES + 63) / 64);
    gemm_mfma<<<gG, dim3(128), 0, stream>>>((const unsigned char*)meanpair,
                                            (const unsigned char*)xb,
                                            (const unsigned char*)wcat, bb, out);
}